// Round 2
// baseline (780.085 us; speedup 1.0000x reference)
//
#include <hip/hip_runtime.h>
#include <math.h>

// Problem constants (fixed by the reference)
#define BB 256
#define TT 512
#define DD 128
#define HH 128
#define GG 512   // 4*H
#define OO 64

// ---------------------------------------------------------------------------
// Fast activations (fp32, v_exp_f32 based; threshold is 5.6e-3, huge headroom)
// ---------------------------------------------------------------------------
__device__ __forceinline__ float sigmoid_fast(float x) {
    return 1.0f / (1.0f + __expf(-x));
}
__device__ __forceinline__ float tanh_fast(float x) {
    // sign(x)*(1 - 2/(exp(2|x|)+1)); overflow-safe: exp->inf => 2/inf=0 => ±1
    float ax = fabsf(x);
    float e = __expf(2.0f * ax);
    float t = 1.0f - 2.0f / (e + 1.0f);
    return copysignf(t, x);
}
__device__ __forceinline__ float readlane_f(float v, int l) {
    return __int_as_float(__builtin_amdgcn_readlane(__float_as_int(v), l));
}

// ---------------------------------------------------------------------------
// Kernel 1: xg[t][g] = dot(x[255,t,:], W_ih[g,:]) + b_ih[g] + b_hh[g]
// Only batch element 255 matters (y.reshape(T,B,O)[-1] -> rows (b=255, t>=256),
// and the LSTM scan for b=255 needs all t). grid = T, block = 512.
// ---------------------------------------------------------------------------
__global__ __launch_bounds__(512) void xg_kernel(
    const float* __restrict__ x,
    const float* __restrict__ W_ih,
    const float* __restrict__ b_ih,
    const float* __restrict__ b_hh,
    float* __restrict__ xg)
{
    const int t = blockIdx.x;
    const int g = threadIdx.x;

    __shared__ __align__(16) float xs[DD];
    if (g < DD) xs[g] = x[(255 * TT + t) * DD + g];
    __syncthreads();

    const float4* __restrict__ wrow = (const float4*)(W_ih + g * DD);
    const float4* __restrict__ xv   = (const float4*)xs;

    float a0 = 0.f, a1 = 0.f, a2 = 0.f, a3 = 0.f;
#pragma unroll
    for (int i = 0; i < DD / 4; i += 4) {
        float4 w0 = wrow[i + 0], w1 = wrow[i + 1], w2 = wrow[i + 2], w3 = wrow[i + 3];
        float4 h0 = xv[i + 0],  h1 = xv[i + 1],  h2 = xv[i + 2],  h3 = xv[i + 3];
        a0 += w0.x * h0.x + w0.y * h0.y + w0.z * h0.z + w0.w * h0.w;
        a1 += w1.x * h1.x + w1.y * h1.y + w1.z * h1.z + w1.w * h1.w;
        a2 += w2.x * h2.x + w2.y * h2.y + w2.z * h2.z + w2.w * h2.w;
        a3 += w3.x * h3.x + w3.y * h3.y + w3.z * h3.z + w3.w * h3.w;
    }
    xg[t * GG + g] = (a0 + a1) + (a2 + a3) + b_ih[g] + b_hh[g];
}

// ---------------------------------------------------------------------------
// Kernel 2: sequential LSTM scan for batch 255. Single block, 256 threads,
// 2 gates per thread (gate g0 = tid, gate g1 = tid+256):
//   tid <  128: g0 = i[tid] (sigmoid), g1 = g[tid] (tanh)    [waves 0,1]
//   tid >= 128: g0 = f[tid-128],       g1 = o[tid-128] (both sigmoid) [waves 2,3]
// Activation choice is wave-uniform -> no divergence.
//
// W_hh rows live in 256 scalar VGPRs per thread (launch_bounds(256,1) gives
// the allocator the full 512-VGPR budget; 1 wave/SIMD, 4 waves total -- fine
// for a 1-block kernel). h is replicated per-wave in registers (lane l holds
// h[l] and h[64+l]); the dot uses v_readlane broadcast: per wave per step
// 128 readlane + 256 fma, ZERO LDS traffic in the inner loop.
// ---------------------------------------------------------------------------
__global__ __launch_bounds__(256, 1) void scan_kernel(
    const float* __restrict__ W_hh,
    const float* __restrict__ xg,
    float* __restrict__ hs)
{
    const int tid  = threadIdx.x;
    const int lane = tid & 63;
    const int g0 = tid;        // i or f
    const int g1 = tid + 256;  // g or o
    const bool low = (tid < HH);   // wave-uniform (waves 0,1)

    __shared__ float fbuf[HH];
    __shared__ float obuf[HH];
    __shared__ float hbuf[HH];

    // --- one-time: weights into registers (256 VGPRs) ---
    float w0[HH], w1[HH];
    {
        const float4* p0 = (const float4*)(W_hh + g0 * HH);
        const float4* p1 = (const float4*)(W_hh + g1 * HH);
#pragma unroll
        for (int i = 0; i < HH / 4; i++) {
            float4 v0 = p0[i], v1 = p1[i];
            w0[4*i+0] = v0.x; w0[4*i+1] = v0.y; w0[4*i+2] = v0.z; w0[4*i+3] = v0.w;
            w1[4*i+0] = v1.x; w1[4*i+1] = v1.y; w1[4*i+2] = v1.z; w1[4*i+3] = v1.w;
        }
    }

    float c  = 0.f;
    float hA = 0.f, hB = 0.f;           // h[lane], h[64+lane], replicated per wave
    float xgA = xg[g0], xgB = xg[g1];   // t = 0 row

    for (int t = 0; t < TT; t++) {
        // prefetch next xg row early (L2-hot); consumed after the dot
        const int tn = (t + 1 < TT) ? (t + 1) : (TT - 1);
        float nA = xg[tn * GG + g0];
        float nB = xg[tn * GG + g1];

        // --- gate pre-activations via register-resident dot + readlane bcast ---
        float acc0 = xgA, acc1 = xgB;
#pragma unroll
        for (int j = 0; j < 64; j++) {
            float hj = readlane_f(hA, j);
            acc0 = fmaf(w0[j], hj, acc0);
            acc1 = fmaf(w1[j], hj, acc1);
        }
#pragma unroll
        for (int j = 0; j < 64; j++) {
            float hj = readlane_f(hB, j);
            acc0 = fmaf(w0[64 + j], hj, acc0);
            acc1 = fmaf(w1[64 + j], hj, acc1);
        }

        // --- activations (wave-uniform branch) ---
        float a0 = sigmoid_fast(acc0);                       // i or f
        float a1 = low ? tanh_fast(acc1) : sigmoid_fast(acc1); // g or o

        if (!low) {            // waves 2,3 publish f, o
            fbuf[tid - HH] = a0;
            obuf[tid - HH] = a1;
        }
        __syncthreads();

        if (low) {             // waves 0,1 update c, h
            float fg = fbuf[tid];
            float og = obuf[tid];
            c = fg * c + a0 * a1;
            float h = og * tanh_fast(c);
            hbuf[tid] = h;
            if (t >= TT - BB) hs[(t - (TT - BB)) * HH + tid] = h;
        }
        __syncthreads();

        hA = hbuf[lane];
        hB = hbuf[64 + lane];
        xgA = nA; xgB = nB;
    }
}

// ---------------------------------------------------------------------------
// Kernel 3: out[r, :] = W2 @ (W1 @ hs[r] + b1) + b2   (no activation in ref)
// grid = 256 blocks (one per output row), block = 128 threads
// ---------------------------------------------------------------------------
__global__ __launch_bounds__(128) void mlp_kernel(
    const float* __restrict__ hs,
    const float* __restrict__ W1,
    const float* __restrict__ b1,
    const float* __restrict__ W2,
    const float* __restrict__ b2,
    float* __restrict__ out)
{
    const int r = blockIdx.x;
    const int j = threadIdx.x;

    __shared__ __align__(16) float hsh[HH];
    __shared__ __align__(16) float z[HH];

    hsh[j] = hs[r * HH + j];
    __syncthreads();

    {
        const float4* __restrict__ wrow = (const float4*)(W1 + j * HH);
        const float4* __restrict__ hv   = (const float4*)hsh;
        float acc = b1[j];
#pragma unroll
        for (int i = 0; i < 32; i++) {
            float4 w = wrow[i], h = hv[i];
            acc += w.x * h.x + w.y * h.y + w.z * h.z + w.w * h.w;
        }
        z[j] = acc;
    }
    __syncthreads();

    if (j < OO) {
        const float4* __restrict__ wrow = (const float4*)(W2 + j * HH);
        const float4* __restrict__ zv   = (const float4*)z;
        float acc = b2[j];
#pragma unroll
        for (int i = 0; i < 32; i++) {
            float4 w = wrow[i], zz = zv[i];
            acc += w.x * zz.x + w.y * zz.y + w.z * zz.z + w.w * zz.w;
        }
        out[r * OO + j] = acc;
    }
}

// ---------------------------------------------------------------------------
// Launch. Inputs (setup_inputs order):
//  0: x (B,T,D)  1: W_ih (4H,D)  2: W_hh (4H,H)  3: b_ih (4H)  4: b_hh (4H)
//  5: W1 (H,H)   6: b1 (H)       7: W2 (O,H)     8: b2 (O)
// Output: (B, O) fp32. Key reduction: y.reshape(T,B,O)[-1] selects b-major
// flat rows (T-1)*B + j -> (b=255, t=256+j). Only batch 255's LSTM is needed.
// ---------------------------------------------------------------------------
extern "C" void kernel_launch(void* const* d_in, const int* in_sizes, int n_in,
                              void* d_out, int out_size, void* d_ws, size_t ws_size,
                              hipStream_t stream) {
    const float* x    = (const float*)d_in[0];
    const float* W_ih = (const float*)d_in[1];
    const float* W_hh = (const float*)d_in[2];
    const float* b_ih = (const float*)d_in[3];
    const float* b_hh = (const float*)d_in[4];
    const float* W1   = (const float*)d_in[5];
    const float* b1   = (const float*)d_in[6];
    const float* W2   = (const float*)d_in[7];
    const float* b2   = (const float*)d_in[8];
    float* out = (float*)d_out;

    float* xg = (float*)d_ws;            // T*4H   = 262144 floats (1 MB)
    float* hs = xg + TT * GG;            // 256*H  =  32768 floats (128 KB)

    xg_kernel<<<TT, 512, 0, stream>>>(x, W_ih, b_ih, b_hh, xg);
    scan_kernel<<<1, 256, 0, stream>>>(W_hh, xg, hs);
    mlp_kernel<<<BB, 128, 0, stream>>>(hs, W1, b1, W2, b2, out);
}

// Round 3
// 430.070 us; speedup vs baseline: 1.8139x; 1.8139x over previous
//
#include <hip/hip_runtime.h>
#include <math.h>

// Problem constants (fixed by the reference)
#define BB 256
#define TT 512
#define DD 128
#define HH 128
#define GG 512   // 4*H
#define OO 64

typedef _Float16 half8 __attribute__((ext_vector_type(8)));
typedef float    f32x4 __attribute__((ext_vector_type(4)));

// ---------------------------------------------------------------------------
// Fast activations (fp32; threshold 5.6e-3, plenty of headroom)
// ---------------------------------------------------------------------------
__device__ __forceinline__ float sigmoid_fast(float x) {
    return 1.0f / (1.0f + __expf(-x));
}
__device__ __forceinline__ float tanh_fast(float x) {
    float ax = fabsf(x);
    float e = __expf(2.0f * ax);
    float t = 1.0f - 2.0f / (e + 1.0f);
    return copysignf(t, x);
}

// ---------------------------------------------------------------------------
// Kernel 0: convert W_hh (f32, 512x128 row-major) -> f16 copy in ws
// ---------------------------------------------------------------------------
__global__ __launch_bounds__(256) void w2h_kernel(
    const float* __restrict__ W, _Float16* __restrict__ W16)
{
    int i = blockIdx.x * 256 + threadIdx.x;   // grid=256 -> 65536 elements
    W16[i] = (_Float16)W[i];
}

// ---------------------------------------------------------------------------
// Kernel 1: xg[t][g] = dot(x[255,t,:], W_ih[g,:]) + b_ih[g] + b_hh[g]
// Only batch 255 matters: y.reshape(T,B,O)[-1] -> flat rows (b=255, t>=256),
// and b=255's scan needs all t. grid = T, block = 512.
// ---------------------------------------------------------------------------
__global__ __launch_bounds__(512) void xg_kernel(
    const float* __restrict__ x,
    const float* __restrict__ W_ih,
    const float* __restrict__ b_ih,
    const float* __restrict__ b_hh,
    float* __restrict__ xg)
{
    const int t = blockIdx.x;
    const int g = threadIdx.x;

    __shared__ __align__(16) float xs[DD];
    if (g < DD) xs[g] = x[(255 * TT + t) * DD + g];
    __syncthreads();

    const float4* __restrict__ wrow = (const float4*)(W_ih + g * DD);
    const float4* __restrict__ xv   = (const float4*)xs;

    float a0 = 0.f, a1 = 0.f, a2 = 0.f, a3 = 0.f;
#pragma unroll
    for (int i = 0; i < DD / 4; i += 4) {
        float4 w0 = wrow[i + 0], w1 = wrow[i + 1], w2 = wrow[i + 2], w3 = wrow[i + 3];
        float4 h0 = xv[i + 0],  h1 = xv[i + 1],  h2 = xv[i + 2],  h3 = xv[i + 3];
        a0 += w0.x * h0.x + w0.y * h0.y + w0.z * h0.z + w0.w * h0.w;
        a1 += w1.x * h1.x + w1.y * h1.y + w1.z * h1.z + w1.w * h1.w;
        a2 += w2.x * h2.x + w2.y * h2.y + w2.z * h2.z + w2.w * h2.w;
        a3 += w3.x * h3.x + w3.y * h3.y + w3.z * h3.z + w3.w * h3.w;
    }
    xg[t * GG + g] = (a0 + a1) + (a2 + a3) + b_ih[g] + b_hh[g];
}

// ---------------------------------------------------------------------------
// Kernel 2: MFMA LSTM scan (batch 255). 1 block, 256 threads = 4 waves.
//
// Per step: pre[g] = xg[t][g] + h . W_hh[g,:]  via v_mfma_f32_16x16x32_f16.
//   - A-frag (16x32): h replicated across all 16 rows -> every C row equals
//     the matvec; lane l supplies A[*][k = (l>>4)*8 + j] = h[kt*32 + ...].
//     4 ds_read_b128 per wave per step (h stored f16 in LDS).
//   - B-frag (32x16): n = lane&15 selects gate row, k = (lane>>4)*8 + j.
//     Wave w owns hidden slice j in [32w, 32w+32), ALL 4 gate types:
//     n-tile (gt,p): gate rows gt*128 + 32w + 16p + (lane&15).
//     Weights live in 32 NAMED half8 SSA values (128 VGPRs) -- no alloca,
//     so the register allocator cannot demote them to scratch (the round-1/2
//     failure mode: promote-alloca refused 512B arrays -> scratch reloads).
//   - C/D layout (m89-verified): col = lane&15; rows identical by construction.
//     i,f,g,o for hidden j land in the SAME lane (C0..C7), update is
//     cross-lane-free. Lane half sel=(lane>=32) picks p=0/1 via cndmask.
// ---------------------------------------------------------------------------
__global__ __launch_bounds__(256, 1) void scan_kernel(
    const _Float16* __restrict__ W16,
    const float* __restrict__ xgp,
    float* __restrict__ hs)
{
    const int tid  = threadIdx.x;
    const int lane = tid & 63;
    const int w    = tid >> 6;        // wave id 0..3
    const int col  = lane & 15;
    const int quad = lane >> 4;
    const int wbase = w * 32;
    const bool sel  = (lane >= 32);                 // p = sel
    const int jsel  = wbase + (sel ? 16 : 0) + col; // hidden index this lane updates

    __shared__ __align__(16) _Float16 h_lds[HH];

    // ---- one-time: B-fragments into named registers ----
    // row(nt) = (nt>>1)*128 + (nt&1)*16 + wbase + col ; elem off = kt*32 + quad*8
#define BLOAD(nt, kt) \
    half8 B##nt##_##kt = *(const half8*)(W16 + \
        (((nt >> 1) * 128 + ((nt) & 1) * 16 + wbase + col) * HH) + (kt) * 32 + quad * 8);
#define FOR_KT(X, nt) X(nt, 0) X(nt, 1) X(nt, 2) X(nt, 3)
#define FOR_NT(X) FOR_KT(X, 0) FOR_KT(X, 1) FOR_KT(X, 2) FOR_KT(X, 3) \
                  FOR_KT(X, 4) FOR_KT(X, 5) FOR_KT(X, 6) FOR_KT(X, 7)
    FOR_NT(BLOAD)

    // init h = 0, c = 0
    if (tid < HH) h_lds[tid] = (_Float16)0.f;
    float c = 0.f;

    // xg for t=0 (per-lane gate values at jsel)
    float xgi = xgp[0 * HH + jsel];
    float xgf = xgp[1 * HH + jsel];
    float xgg = xgp[2 * HH + jsel];
    float xgo = xgp[3 * HH + jsel];

    __syncthreads();

    const _Float16* hl = (const _Float16*)h_lds;
    const int aoff = quad * 8;

    for (int t = 0; t < TT; t++) {
        // ---- A-fragments: h replicated over rows ----
        half8 A0 = *(const half8*)(hl + 0 * 32 + aoff);
        half8 A1 = *(const half8*)(hl + 1 * 32 + aoff);
        half8 A2 = *(const half8*)(hl + 2 * 32 + aoff);
        half8 A3 = *(const half8*)(hl + 3 * 32 + aoff);
        __syncthreads();   // all reads of old h done before anyone writes

        // prefetch next step's xg row (vmem overlaps the MFMAs)
        const int tn = (t + 1 < TT) ? (t + 1) : (TT - 1);
        float xgi_n = xgp[tn * GG + 0 * HH + jsel];
        float xgf_n = xgp[tn * GG + 1 * HH + jsel];
        float xgg_n = xgp[tn * GG + 2 * HH + jsel];
        float xgo_n = xgp[tn * GG + 3 * HH + jsel];

        // ---- 32 MFMAs: 8 n-tiles x 4 k-tiles (kt-outer: early start, dep spacing)
        f32x4 C0 = {0.f,0.f,0.f,0.f}, C1 = {0.f,0.f,0.f,0.f};
        f32x4 C2 = {0.f,0.f,0.f,0.f}, C3 = {0.f,0.f,0.f,0.f};
        f32x4 C4 = {0.f,0.f,0.f,0.f}, C5 = {0.f,0.f,0.f,0.f};
        f32x4 C6 = {0.f,0.f,0.f,0.f}, C7 = {0.f,0.f,0.f,0.f};
#define MF(nt, kt) \
        C##nt = __builtin_amdgcn_mfma_f32_16x16x32_f16(A##kt, B##nt##_##kt, C##nt, 0, 0, 0);
#define MF_ALLNT(kt) MF(0, kt) MF(1, kt) MF(2, kt) MF(3, kt) \
                     MF(4, kt) MF(5, kt) MF(6, kt) MF(7, kt)
        MF_ALLNT(0) MF_ALLNT(1) MF_ALLNT(2) MF_ALLNT(3)

        // ---- epilogue: gates for hidden jsel (this lane) ----
        float pi = (sel ? C1[0] : C0[0]) + xgi;
        float pf = (sel ? C3[0] : C2[0]) + xgf;
        float pg = (sel ? C5[0] : C4[0]) + xgg;
        float po = (sel ? C7[0] : C6[0]) + xgo;

        float iv = sigmoid_fast(pi);
        float fv = sigmoid_fast(pf);
        float gv = tanh_fast(pg);
        float ov = sigmoid_fast(po);

        c = fv * c + iv * gv;
        float h = ov * tanh_fast(c);

        // one writer per hidden index: quad 0 (sel=0) and quad 3 (sel=1)
        if (quad == 0 || quad == 3) {
            h_lds[jsel] = (_Float16)h;
            if (t >= TT - BB) hs[(t - (TT - BB)) * HH + jsel] = h;
        }

        xgi = xgi_n; xgf = xgf_n; xgg = xgg_n; xgo = xgo_n;
        __syncthreads();   // new h visible before next A-read
    }
}

// ---------------------------------------------------------------------------
// Kernel 3: out[r,:] = W2 @ (W1 @ hs[r] + b1) + b2  (no activation in ref)
// ---------------------------------------------------------------------------
__global__ __launch_bounds__(128) void mlp_kernel(
    const float* __restrict__ hs,
    const float* __restrict__ W1,
    const float* __restrict__ b1,
    const float* __restrict__ W2,
    const float* __restrict__ b2,
    float* __restrict__ out)
{
    const int r = blockIdx.x;
    const int j = threadIdx.x;

    __shared__ __align__(16) float hsh[HH];
    __shared__ __align__(16) float z[HH];

    hsh[j] = hs[r * HH + j];
    __syncthreads();

    {
        const float4* __restrict__ wrow = (const float4*)(W1 + j * HH);
        const float4* __restrict__ hv   = (const float4*)hsh;
        float acc = b1[j];
#pragma unroll
        for (int i = 0; i < 32; i++) {
            float4 ww = wrow[i], h = hv[i];
            acc += ww.x * h.x + ww.y * h.y + ww.z * h.z + ww.w * h.w;
        }
        z[j] = acc;
    }
    __syncthreads();

    if (j < OO) {
        const float4* __restrict__ wrow = (const float4*)(W2 + j * HH);
        const float4* __restrict__ zv   = (const float4*)z;
        float acc = b2[j];
#pragma unroll
        for (int i = 0; i < 32; i++) {
            float4 ww = wrow[i], zz = zv[i];
            acc += ww.x * zz.x + ww.y * zz.y + ww.z * zz.z + ww.w * zz.w;
        }
        out[r * OO + j] = acc;
    }
}

// ---------------------------------------------------------------------------
// Launch. Inputs: 0:x 1:W_ih 2:W_hh 3:b_ih 4:b_hh 5:W1 6:b1 7:W2 8:b2
// ws: xg (1 MB) | hs (128 KB) | W16 (128 KB)
// ---------------------------------------------------------------------------
extern "C" void kernel_launch(void* const* d_in, const int* in_sizes, int n_in,
                              void* d_out, int out_size, void* d_ws, size_t ws_size,
                              hipStream_t stream) {
    const float* x    = (const float*)d_in[0];
    const float* W_ih = (const float*)d_in[1];
    const float* W_hh = (const float*)d_in[2];
    const float* b_ih = (const float*)d_in[3];
    const float* b_hh = (const float*)d_in[4];
    const float* W1   = (const float*)d_in[5];
    const float* b1   = (const float*)d_in[6];
    const float* W2   = (const float*)d_in[7];
    const float* b2   = (const float*)d_in[8];
    float* out = (float*)d_out;

    float*     xg  = (float*)d_ws;           // T*4H = 262144 f32
    float*     hs  = xg + TT * GG;           // 256*H = 32768 f32
    _Float16*  W16 = (_Float16*)(hs + BB * HH); // 4H*H = 65536 f16

    w2h_kernel<<<256, 256, 0, stream>>>(W_hh, W16);
    xg_kernel<<<TT, 512, 0, stream>>>(x, W_ih, b_ih, b_hh, xg);
    scan_kernel<<<1, 256, 0, stream>>>(W16, xg, hs);
    mlp_kernel<<<BB, 128, 0, stream>>>(hs, W1, b1, W2, b2, out);
}